// Round 8
// baseline (380.666 us; speedup 1.0000x reference)
//
#include <hip/hip_runtime.h>

#define B_ROWS 4096
#define K_Q    32768
#define D_DIM  256
#define C_CLS  100

typedef unsigned short u16;
typedef __attribute__((ext_vector_type(8))) short short8_t;   // 8 bf16 (4 VGPR)
typedef __attribute__((ext_vector_type(4))) float f32x4;

__device__ inline u16 f2bf(float x) {   // RNE float->bf16
  unsigned int u = __float_as_uint(x);
  u = (u + 0x7FFFu + ((u >> 16) & 1u)) >> 16;
  return (u16)u;
}

__device__ inline float fast_sqrt(float x) {    // single v_sqrt_f32
  return __builtin_amdgcn_sqrtf(x);
}

// ---------- K1: fused per-class histogram + fp32->bf16 cast of Q ----------
__global__ void k_histcast(const float* __restrict__ q, const int* __restrict__ lab,
                           int* __restrict__ counts, float* __restrict__ sums,
                           u16* __restrict__ qbf) {
  const int kc = blockIdx.x;          // 128 chunks of 256 queue rows
  const int dc = blockIdx.y;          // 4 chunks of 64 cols
  __shared__ float lsum[C_CLS * 64];
  __shared__ int lcnt[C_CLS];
  const int tid = threadIdx.x;
  for (int i = tid; i < C_CLS * 64; i += 256) lsum[i] = 0.f;
  if (dc == 0 && tid < C_CLS) lcnt[tid] = 0;
  __syncthreads();

  const int rloc = tid >> 4;          // 16 rows per iteration
  const int c4 = tid & 15;            // float4 slot within 64 cols
  for (int it = 0; it < 16; ++it) {
    const int k = kc * 256 + it * 16 + rloc;
    const int c = lab[k];
    const size_t off = (size_t)k * D_DIM + dc * 64 + c4 * 4;
    float4 v = *(const float4*)(q + off);
    ushort4 o;
    o.x = f2bf(v.x); o.y = f2bf(v.y); o.z = f2bf(v.z); o.w = f2bf(v.w);
    *(ushort4*)(qbf + off) = o;
    const int base = c * 64 + c4 * 4;
    atomicAdd(&lsum[base + 0], v.x);
    atomicAdd(&lsum[base + 1], v.y);
    atomicAdd(&lsum[base + 2], v.z);
    atomicAdd(&lsum[base + 3], v.w);
    if (dc == 0 && c4 == 0) atomicAdd(&lcnt[c], 1);
  }
  __syncthreads();
  for (int i = tid; i < C_CLS * 64; i += 256) {
    int c = i >> 6, d = i & 63;
    atomicAdd(&sums[c * D_DIM + dc * 64 + d], lsum[i]);
  }
  if (dc == 0 && tid < C_CLS) atomicAdd(&counts[tid], lcnt[tid]);
}

// ---------- K2: centroid normalize ----------
__global__ void k_cnorm(const int* __restrict__ counts, const float* __restrict__ sums,
                        float* __restrict__ cnorm) {
  __shared__ float red[4];
  const int c = blockIdx.x, d = threadIdx.x;
  float cnt = (float)counts[c];
  float v = sums[c * D_DIM + d] / cnt;
  float ss = v * v;
  #pragma unroll
  for (int o = 1; o < 64; o <<= 1) ss += __shfl_xor(ss, o);
  if ((d & 63) == 0) red[d >> 6] = ss;
  __syncthreads();
  float norm = sqrtf(red[0] + red[1] + red[2] + red[3]);
  cnorm[c * D_DIM + d] = v / fmaxf(norm, 1e-12f);
}

// ---------- K3: pseudo-labels (fp32 argmax) + fused A bf16 cast ----------
__global__ void k_pseudo(const float* __restrict__ bf, const float* __restrict__ cn,
                         int* __restrict__ pseudo, u16* __restrict__ abf) {
  const int tid = threadIdx.x;
  const int rloc = tid >> 4;                    // 16 rows/block
  const int sub = tid & 15;                     // 16 lanes/row
  const int row = blockIdx.x * 16 + rloc;
  float4 a[4];
  const float4* ap = (const float4*)(bf + (size_t)row * D_DIM);
  #pragma unroll
  for (int j = 0; j < 4; ++j) a[j] = ap[sub + j * 16];
  #pragma unroll
  for (int j = 0; j < 4; ++j) {
    ushort4 o;
    o.x = f2bf(a[j].x); o.y = f2bf(a[j].y); o.z = f2bf(a[j].z); o.w = f2bf(a[j].w);
    *(ushort4*)(abf + (size_t)row * D_DIM + (sub + j * 16) * 4) = o;
  }
  float best = -1e30f; int bi = 0;
  for (int c = 0; c < C_CLS; ++c) {
    const float4* cp = (const float4*)(cn + c * D_DIM);
    float s = 0.f;
    #pragma unroll
    for (int j = 0; j < 4; ++j) {
      float4 b = cp[sub + j * 16];
      s += a[j].x * b.x + a[j].y * b.y + a[j].z * b.z + a[j].w * b.w;
    }
    s += __shfl_xor(s, 1); s += __shfl_xor(s, 2);
    s += __shfl_xor(s, 4); s += __shfl_xor(s, 8);
    if (s > best) { best = s; bi = c; }         // strict > = first index (jnp.argmax)
  }
  if (sub == 0) pseudo[row] = bi;
}

// ---------- K5: fused bf16 MFMA GEMM + sqrt + masked row-sums (no LDS) ----------
// 2048 blocks x 256 thr (4 waves, 2wr x 2wc). Wave = 32 rows x 32 cols per step.
// Block = 64 rows x 1024-col slice, 16 steps of 64 cols. A-frags resident in regs.
// KEY (R8): amdgpu_waves_per_eu(3,3) pins the scheduler's occupancy TARGET at
// 3 waves/EU (VGPR budget 168). R5-R7's VGPR=60 was the max-occupancy scheduler
// remat'ing/spilling areg to hit 8 waves/EU (64-VGPR budget); __launch_bounds__
// only sets the minimum, so it couldn't prevent that.
__global__ __attribute__((amdgpu_flat_work_group_size(256, 256), amdgpu_waves_per_eu(3, 3)))
void k_main(
    const u16* __restrict__ Abf, const u16* __restrict__ Qbf,
    const int* __restrict__ lab, const int* __restrict__ pseudo,
    float* __restrict__ S_all, float* __restrict__ S_match) {
  // XCD-bijective swizzle (2048 % 8 == 0).
  const int bid = blockIdx.x;
  const int o = (bid & 7) * 256 + (bid >> 3);
  const int cs = o >> 6;              // 0..31 col slice (1024 cols)
  const int rb = o & 63;              // 0..63 row block (64 rows)

  const int tid = threadIdx.x;
  const int w = tid >> 6;
  const int wr = w >> 1, wc = w & 1;
  const int l = tid & 63;
  const int q16 = l & 15, hi = l >> 4;
  const int rowA = rb * 64 + wr * 32;           // wave's 32 rows
  const int colW = cs * 1024 + wc * 32;         // wave's col base within slice

  // A-fragments: 2(m) x 8(kt) short8 = 64 VGPR, loaded once, resident.
  short8_t areg[2][8];
  #pragma unroll
  for (int m = 0; m < 2; ++m)
    #pragma unroll
    for (int kt = 0; kt < 8; ++kt)
      areg[m][kt] = *(const short8_t*)(Abf + (size_t)(rowA + m * 16 + q16) * D_DIM + kt * 32 + hi * 8);

  int pse[2][4];
  #pragma unroll
  for (int m = 0; m < 2; ++m)
    #pragma unroll
    for (int j = 0; j < 4; ++j)
      pse[m][j] = pseudo[rowA + m * 16 + hi * 4 + j];

  float pa[2][4], pm_[2][4];
  #pragma unroll
  for (int m = 0; m < 2; ++m)
    #pragma unroll
    for (int j = 0; j < 4; ++j) { pa[m][j] = 0.f; pm_[m][j] = 0.f; }

  const u16* bbase = Qbf + (size_t)(colW + q16) * D_DIM + hi * 8;
  const int* lbase = lab + colW + q16;

  #pragma unroll 1
  for (int cb = 0; cb < 16; ++cb) {
    const int lbl0 = lbase[cb * 64];
    const int lbl1 = lbase[cb * 64 + 16];

    f32x4 acc[2][2];
    #pragma unroll
    for (int m = 0; m < 2; ++m)
      #pragma unroll
      for (int n = 0; n < 2; ++n)
        #pragma unroll
        for (int j = 0; j < 4; ++j) acc[m][n][j] = 0.f;

    const u16* bp = bbase + (size_t)(cb * 64) * D_DIM;
    #pragma unroll
    for (int kt = 0; kt < 8; ++kt) {
      short8_t b0 = *(const short8_t*)(bp + kt * 32);
      short8_t b1 = *(const short8_t*)(bp + 16 * D_DIM + kt * 32);
      acc[0][0] = __builtin_amdgcn_mfma_f32_16x16x32_bf16(areg[0][kt], b0, acc[0][0], 0, 0, 0);
      acc[1][0] = __builtin_amdgcn_mfma_f32_16x16x32_bf16(areg[1][kt], b0, acc[1][0], 0, 0, 0);
      acc[0][1] = __builtin_amdgcn_mfma_f32_16x16x32_bf16(areg[0][kt], b1, acc[0][1], 0, 0, 0);
      acc[1][1] = __builtin_amdgcn_mfma_f32_16x16x32_bf16(areg[1][kt], b1, acc[1][1], 0, 0, 0);
    }

    // MAE epilogue (registers only)
    #pragma unroll
    for (int m = 0; m < 2; ++m)
      #pragma unroll
      for (int j = 0; j < 4; ++j) {
        const int p = pse[m][j];
        float mae0 = fast_sqrt(fmaxf(__builtin_fmaf(-2.0f, acc[m][0][j], 2.000001f), 0.0f));
        float mae1 = fast_sqrt(fmaxf(__builtin_fmaf(-2.0f, acc[m][1][j], 2.000001f), 0.0f));
        pa[m][j] += mae0 + mae1;
        pm_[m][j] += (lbl0 == p ? mae0 : 0.0f) + (lbl1 == p ? mae1 : 0.0f);
      }
  }

  // once per block: reduce over 16 q-lanes, then atomics
  #pragma unroll
  for (int m = 0; m < 2; ++m)
    #pragma unroll
    for (int j = 0; j < 4; ++j) {
      float va = pa[m][j], vm = pm_[m][j];
      va += __shfl_xor(va, 1); va += __shfl_xor(va, 2);
      va += __shfl_xor(va, 4); va += __shfl_xor(va, 8);
      vm += __shfl_xor(vm, 1); vm += __shfl_xor(vm, 2);
      vm += __shfl_xor(vm, 4); vm += __shfl_xor(vm, 8);
      if (q16 == 0) {
        const int gr = rowA + m * 16 + hi * 4 + j;
        atomicAdd(&S_all[gr], va);
        atomicAdd(&S_match[gr], vm);
      }
    }
}

// ---------- K6: final scalar ----------
__global__ void k_final(const float* __restrict__ S_all, const float* __restrict__ S_match,
                        const int* __restrict__ pseudo, const int* __restrict__ counts,
                        float* __restrict__ out) {
  __shared__ float r1[16], r2[16];
  const int tid = threadIdx.x;
  float s1 = 0.f, s2 = 0.f;
  for (int b = tid; b < B_ROWS; b += 1024) {
    float cnt = (float)counts[pseudo[b]];
    float sm = S_match[b], sa = S_all[b];
    s1 += sm / (cnt + 1e-6f);
    s2 += (sa - sm) / ((float)K_Q - cnt + 1e-6f);
  }
  #pragma unroll
  for (int o = 1; o < 64; o <<= 1) { s1 += __shfl_xor(s1, o); s2 += __shfl_xor(s2, o); }
  if ((tid & 63) == 0) { r1[tid >> 6] = s1; r2[tid >> 6] = s2; }
  __syncthreads();
  if (tid == 0) {
    float t1 = 0.f, t2 = 0.f;
    #pragma unroll
    for (int i = 0; i < 16; ++i) { t1 += r1[i]; t2 += r2[i]; }
    out[0] = t1 / (float)B_ROWS + 2.0f - t2 / (float)B_ROWS;
  }
}

extern "C" void kernel_launch(void* const* d_in, const int* in_sizes, int n_in,
                              void* d_out, int out_size, void* d_ws, size_t ws_size,
                              hipStream_t stream) {
  const float* batch = (const float*)d_in[0];
  const float* queue = (const float*)d_in[1];
  const int*   lab   = (const int*)d_in[2];

  char* ws = (char*)d_ws;
  int*   counts  = (int*)  (ws + 0);
  float* sums    = (float*)(ws + 512);
  float* S_all   = (float*)(ws + 102912);
  float* S_match = (float*)(ws + 119296);
  float* cnorm   = (float*)(ws + 135680);
  int*   pseudo  = (int*)  (ws + 238080);
  u16*   Abf     = (u16*)  (ws + 254464);
  u16*   Qbf     = (u16*)  (ws + 254464 + 2097152);

  (void)hipMemsetAsync(d_ws, 0, 135680, stream);  // counts+sums+S_all+S_match

  k_histcast<<<dim3(128, 4), 256, 0, stream>>>(queue, lab, counts, sums, Qbf);
  k_cnorm   <<<C_CLS, 256, 0, stream>>>(counts, sums, cnorm);
  k_pseudo  <<<B_ROWS / 16, 256, 0, stream>>>(batch, cnorm, pseudo, Abf);
  k_main    <<<2048, 256, 0, stream>>>(Abf, Qbf, lab, pseudo, S_all, S_match);
  k_final   <<<1, 1024, 0, stream>>>(S_all, S_match, pseudo, counts, (float*)d_out);
}

// Round 9
// 209.931 us; speedup vs baseline: 1.8133x; 1.8133x over previous
//
#include <hip/hip_runtime.h>

#define B_ROWS 4096
#define K_Q    32768
#define D_DIM  256
#define C_CLS  100

typedef unsigned short u16;
typedef __attribute__((ext_vector_type(8))) short short8_t;   // 8 bf16 (4 VGPR)
typedef __attribute__((ext_vector_type(4))) float f32x4;

__device__ inline u16 f2bf(float x) {   // RNE float->bf16
  unsigned int u = __float_as_uint(x);
  u = (u + 0x7FFFu + ((u >> 16) & 1u)) >> 16;
  return (u16)u;
}

__device__ inline float fast_sqrt(float x) {    // single v_sqrt_f32
  return __builtin_amdgcn_sqrtf(x);
}

#define GLDS16(g, l) __builtin_amdgcn_global_load_lds( \
    (const __attribute__((address_space(1))) unsigned int*)(g), \
    (__attribute__((address_space(3))) unsigned int*)(l), 16, 0, 0)

// ---------- K1: fused per-class histogram + fp32->bf16 cast of Q ----------
__global__ void k_histcast(const float* __restrict__ q, const int* __restrict__ lab,
                           int* __restrict__ counts, float* __restrict__ sums,
                           u16* __restrict__ qbf) {
  const int kc = blockIdx.x;          // 128 chunks of 256 queue rows
  const int dc = blockIdx.y;          // 4 chunks of 64 cols
  __shared__ float lsum[C_CLS * 64];
  __shared__ int lcnt[C_CLS];
  const int tid = threadIdx.x;
  for (int i = tid; i < C_CLS * 64; i += 256) lsum[i] = 0.f;
  if (dc == 0 && tid < C_CLS) lcnt[tid] = 0;
  __syncthreads();

  const int rloc = tid >> 4;          // 16 rows per iteration
  const int c4 = tid & 15;            // float4 slot within 64 cols
  for (int it = 0; it < 16; ++it) {
    const int k = kc * 256 + it * 16 + rloc;
    const int c = lab[k];
    const size_t off = (size_t)k * D_DIM + dc * 64 + c4 * 4;
    float4 v = *(const float4*)(q + off);
    ushort4 o;
    o.x = f2bf(v.x); o.y = f2bf(v.y); o.z = f2bf(v.z); o.w = f2bf(v.w);
    *(ushort4*)(qbf + off) = o;
    const int base = c * 64 + c4 * 4;
    atomicAdd(&lsum[base + 0], v.x);
    atomicAdd(&lsum[base + 1], v.y);
    atomicAdd(&lsum[base + 2], v.z);
    atomicAdd(&lsum[base + 3], v.w);
    if (dc == 0 && c4 == 0) atomicAdd(&lcnt[c], 1);
  }
  __syncthreads();
  for (int i = tid; i < C_CLS * 64; i += 256) {
    int c = i >> 6, d = i & 63;
    atomicAdd(&sums[c * D_DIM + dc * 64 + d], lsum[i]);
  }
  if (dc == 0 && tid < C_CLS) atomicAdd(&counts[tid], lcnt[tid]);
}

// ---------- K2: centroid normalize ----------
__global__ void k_cnorm(const int* __restrict__ counts, const float* __restrict__ sums,
                        float* __restrict__ cnorm) {
  __shared__ float red[4];
  const int c = blockIdx.x, d = threadIdx.x;
  float cnt = (float)counts[c];
  float v = sums[c * D_DIM + d] / cnt;
  float ss = v * v;
  #pragma unroll
  for (int o = 1; o < 64; o <<= 1) ss += __shfl_xor(ss, o);
  if ((d & 63) == 0) red[d >> 6] = ss;
  __syncthreads();
  float norm = sqrtf(red[0] + red[1] + red[2] + red[3]);
  cnorm[c * D_DIM + d] = v / fmaxf(norm, 1e-12f);
}

// ---------- K3: pseudo-labels (fp32 argmax) + fused A bf16 cast ----------
__global__ void k_pseudo(const float* __restrict__ bf, const float* __restrict__ cn,
                         int* __restrict__ pseudo, u16* __restrict__ abf) {
  const int tid = threadIdx.x;
  const int rloc = tid >> 4;                    // 16 rows/block
  const int sub = tid & 15;                     // 16 lanes/row
  const int row = blockIdx.x * 16 + rloc;
  float4 a[4];
  const float4* ap = (const float4*)(bf + (size_t)row * D_DIM);
  #pragma unroll
  for (int j = 0; j < 4; ++j) a[j] = ap[sub + j * 16];
  #pragma unroll
  for (int j = 0; j < 4; ++j) {
    ushort4 o;
    o.x = f2bf(a[j].x); o.y = f2bf(a[j].y); o.z = f2bf(a[j].z); o.w = f2bf(a[j].w);
    *(ushort4*)(abf + (size_t)row * D_DIM + (sub + j * 16) * 4) = o;
  }
  float best = -1e30f; int bi = 0;
  for (int c = 0; c < C_CLS; ++c) {
    const float4* cp = (const float4*)(cn + c * D_DIM);
    float s = 0.f;
    #pragma unroll
    for (int j = 0; j < 4; ++j) {
      float4 b = cp[sub + j * 16];
      s += a[j].x * b.x + a[j].y * b.y + a[j].z * b.z + a[j].w * b.w;
    }
    s += __shfl_xor(s, 1); s += __shfl_xor(s, 2);
    s += __shfl_xor(s, 4); s += __shfl_xor(s, 8);
    if (s > best) { best = s; bi = c; }         // strict > = first index (jnp.argmax)
  }
  if (sub == 0) pseudo[row] = bi;
}

// ---------- K5: fused bf16 MFMA GEMM + sqrt + masked row-sums ----------
// B through LDS (broadcast to 4 row-stacked waves); A resident in regs/AGPRs.
// Block: 4 waves x 64 rows = 256 rows, sweeping a 1024-col slice in 32 steps
// of 32 cols. Per step: stage next B-tile (16KB) via global_load_lds (linear
// dest, pre-swizzled source), 1 barrier, ds_read_b128 swizzled (uniform
// 8 lanes/granule = conflict-free), 128 MFMA/wave... m-rep 4, n-rep 2.
// Per-CU: LDS-read 128KB/cb (~1150cy) < MFMA 512x4.85 (~2480cy) -> MFMA-bound.
__global__ __launch_bounds__(256) void k_main(
    const u16* __restrict__ Abf, const u16* __restrict__ Qbf,
    const int* __restrict__ lab, const int* __restrict__ pseudo,
    float* __restrict__ S_all, float* __restrict__ S_match) {
  __shared__ u16 Bs[2][32 * 256];     // 2 x 16KB: [col:32][k-chunks, XOR-swizzled]

  // XCD-bijective: grid 512 = 16 rb x 32 cs; per XCD 64 blocks = 4 cs x 16 rb
  // -> 4 col-slices (2MB Qbf) + all A (2MB) = 4MB L2.
  const int bid = blockIdx.x;
  const int xcd = bid & 7, idx = bid >> 3;      // idx 0..63
  const int cs = xcd * 4 + (idx >> 4);          // 0..31
  const int rb = idx & 15;                      // 0..15

  const int tid = threadIdx.x;
  const int w = tid >> 6;                       // 4 waves, row-stacked
  const int l = tid & 63;
  const int q16 = l & 15, hi = l >> 4;
  const int rowA = rb * 256 + w * 64;           // wave's 64 rows
  const int colbase = cs * 1024;

  // A-fragments: 4(m) x 8(kt) short8 = 128 regs (AGPR-parked), loaded once.
  short8_t areg[4][8];
  #pragma unroll
  for (int m = 0; m < 4; ++m)
    #pragma unroll
    for (int kt = 0; kt < 8; ++kt)
      areg[m][kt] = *(const short8_t*)(Abf + (size_t)(rowA + m * 16 + q16) * D_DIM + kt * 32 + hi * 8);

  // pseudo-labels for rows rowA + m*16 + hi*4 + j, byte-packed (C<256)
  int psepk[4];
  #pragma unroll
  for (int m = 0; m < 4; ++m) {
    const int* pp = pseudo + rowA + m * 16 + hi * 4;
    psepk[m] = pp[0] | (pp[1] << 8) | (pp[2] << 16) | (pp[3] << 24);
  }

  float pa[4][4], pm_[4][4];
  #pragma unroll
  for (int m = 0; m < 4; ++m)
    #pragma unroll
    for (int j = 0; j < 4; ++j) { pa[m][j] = 0.f; pm_[m][j] = 0.f; }

  // Staging map (rule #21: linear LDS dest, inverse-swizzled global source).
  // Instr i, thread t: LDS bytes [i*4096 + t*16); row r = i*8 + (t>>5),
  // lds-chunk q = t&31 holds global chunk q ^ (r&7); r&7 == (t>>5)&7.
  const int srow_ = tid >> 5;                   // 0..7
  const int schunk = (tid & 31) ^ (srow_ & 7);
  const u16* sbase = Qbf + (size_t)(colbase + srow_) * D_DIM + schunk * 8;
  u16* lbase_lds0 = &Bs[0][0];
  u16* lbase_lds1 = &Bs[1][0];

#define STAGE(lds, cboff)                                              \
  {                                                                    \
    const u16* s_ = sbase + (size_t)(cboff) * (32 * D_DIM);            \
    _Pragma("unroll")                                                  \
    for (int i_ = 0; i_ < 4; ++i_)                                     \
      GLDS16(s_ + i_ * (8 * D_DIM), (lds) + i_ * 2048 + tid * 8);      \
  }

  const int* lptr = lab + colbase + q16;
  const int xorm = (q16 & 7) << 4;              // read-side swizzle (bytes)

  STAGE(lbase_lds0, 0);                          // prologue: cb=0 -> buf0

  #pragma unroll 1
  for (int cb = 0; cb < 32; ++cb) {
    __syncthreads();                             // buf[cb&1] ready (drains vmcnt)
    if (cb + 1 < 32) {                           // prefetch next across compute
      if ((cb & 1) == 0) STAGE(lbase_lds1, cb + 1)
      else               STAGE(lbase_lds0, cb + 1)
    }
    const int lbl0 = lptr[cb * 32];
    const int lbl1 = lptr[cb * 32 + 16];

    const char* bs = (const char*)&Bs[cb & 1][0];
    f32x4 acc[4][2];
    #pragma unroll
    for (int m = 0; m < 4; ++m)
      #pragma unroll
      for (int n = 0; n < 2; ++n)
        #pragma unroll
        for (int j = 0; j < 4; ++j) acc[m][n][j] = 0.f;

    #pragma unroll
    for (int kt = 0; kt < 8; ++kt) {
      const int koff = (kt * 64 + hi * 16) ^ xorm;
      short8_t b0 = *(const short8_t*)(bs + q16 * 512 + koff);
      short8_t b1 = *(const short8_t*)(bs + (16 + q16) * 512 + koff);
      #pragma unroll
      for (int m = 0; m < 4; ++m)
        acc[m][0] = __builtin_amdgcn_mfma_f32_16x16x32_bf16(areg[m][kt], b0, acc[m][0], 0, 0, 0);
      #pragma unroll
      for (int m = 0; m < 4; ++m)
        acc[m][1] = __builtin_amdgcn_mfma_f32_16x16x32_bf16(areg[m][kt], b1, acc[m][1], 0, 0, 0);
    }

    // MAE epilogue (registers only)
    #pragma unroll
    for (int m = 0; m < 4; ++m)
      #pragma unroll
      for (int j = 0; j < 4; ++j) {
        const int p = (psepk[m] >> (8 * j)) & 255;
        float mae0 = fast_sqrt(fmaxf(__builtin_fmaf(-2.0f, acc[m][0][j], 2.000001f), 0.0f));
        float mae1 = fast_sqrt(fmaxf(__builtin_fmaf(-2.0f, acc[m][1][j], 2.000001f), 0.0f));
        pa[m][j] += mae0 + mae1;
        pm_[m][j] += (lbl0 == p ? mae0 : 0.0f) + (lbl1 == p ? mae1 : 0.0f);
      }
  }

  // once per block: reduce over 16 q-lanes, then atomics
  #pragma unroll
  for (int m = 0; m < 4; ++m)
    #pragma unroll
    for (int j = 0; j < 4; ++j) {
      float va = pa[m][j], vm = pm_[m][j];
      va += __shfl_xor(va, 1); va += __shfl_xor(va, 2);
      va += __shfl_xor(va, 4); va += __shfl_xor(va, 8);
      vm += __shfl_xor(vm, 1); vm += __shfl_xor(vm, 2);
      vm += __shfl_xor(vm, 4); vm += __shfl_xor(vm, 8);
      if (q16 == 0) {
        const int gr = rowA + m * 16 + hi * 4 + j;
        atomicAdd(&S_all[gr], va);
        atomicAdd(&S_match[gr], vm);
      }
    }
#undef STAGE
}

// ---------- K6: final scalar ----------
__global__ void k_final(const float* __restrict__ S_all, const float* __restrict__ S_match,
                        const int* __restrict__ pseudo, const int* __restrict__ counts,
                        float* __restrict__ out) {
  __shared__ float r1[16], r2[16];
  const int tid = threadIdx.x;
  float s1 = 0.f, s2 = 0.f;
  for (int b = tid; b < B_ROWS; b += 1024) {
    float cnt = (float)counts[pseudo[b]];
    float sm = S_match[b], sa = S_all[b];
    s1 += sm / (cnt + 1e-6f);
    s2 += (sa - sm) / ((float)K_Q - cnt + 1e-6f);
  }
  #pragma unroll
  for (int o = 1; o < 64; o <<= 1) { s1 += __shfl_xor(s1, o); s2 += __shfl_xor(s2, o); }
  if ((tid & 63) == 0) { r1[tid >> 6] = s1; r2[tid >> 6] = s2; }
  __syncthreads();
  if (tid == 0) {
    float t1 = 0.f, t2 = 0.f;
    #pragma unroll
    for (int i = 0; i < 16; ++i) { t1 += r1[i]; t2 += r2[i]; }
    out[0] = t1 / (float)B_ROWS + 2.0f - t2 / (float)B_ROWS;
  }
}

extern "C" void kernel_launch(void* const* d_in, const int* in_sizes, int n_in,
                              void* d_out, int out_size, void* d_ws, size_t ws_size,
                              hipStream_t stream) {
  const float* batch = (const float*)d_in[0];
  const float* queue = (const float*)d_in[1];
  const int*   lab   = (const int*)d_in[2];

  char* ws = (char*)d_ws;
  int*   counts  = (int*)  (ws + 0);
  float* sums    = (float*)(ws + 512);
  float* S_all   = (float*)(ws + 102912);
  float* S_match = (float*)(ws + 119296);
  float* cnorm   = (float*)(ws + 135680);
  int*   pseudo  = (int*)  (ws + 238080);
  u16*   Abf     = (u16*)  (ws + 254464);
  u16*   Qbf     = (u16*)  (ws + 254464 + 2097152);

  (void)hipMemsetAsync(d_ws, 0, 135680, stream);  // counts+sums+S_all+S_match

  k_histcast<<<dim3(128, 4), 256, 0, stream>>>(queue, lab, counts, sums, Qbf);
  k_cnorm   <<<C_CLS, 256, 0, stream>>>(counts, sums, cnorm);
  k_pseudo  <<<B_ROWS / 16, 256, 0, stream>>>(batch, cnorm, pseudo, Abf);
  k_main    <<<512, 256, 0, stream>>>(Abf, Qbf, lab, pseudo, S_all, S_match);
  k_final   <<<1, 1024, 0, stream>>>(S_all, S_match, pseudo, counts, (float*)d_out);
}

// Round 10
// 174.254 us; speedup vs baseline: 2.1845x; 1.2047x over previous
//
#include <hip/hip_runtime.h>

#define B_ROWS 4096
#define K_Q    32768
#define D_DIM  256
#define C_CLS  100

typedef unsigned short u16;
typedef unsigned char u8;
typedef long i64;                                // 64-bit on amdgcn
typedef __attribute__((ext_vector_type(4))) float f32x4;

__device__ inline float fast_sqrt(float x) { return __builtin_amdgcn_sqrtf(x); }

// pack float4*16 -> 4 fp8 e4m3 bytes (OCP on gfx950, RNE, saturating)
__device__ inline unsigned int pk4_fp8(float4 v) {
  int lo = __builtin_amdgcn_cvt_pk_fp8_f32(v.x * 16.f, v.y * 16.f, 0, false);
  int r  = __builtin_amdgcn_cvt_pk_fp8_f32(v.z * 16.f, v.w * 16.f, lo, true);
  return (unsigned int)r;
}

#define GLDS16(g, l) __builtin_amdgcn_global_load_lds( \
    (const __attribute__((address_space(1))) unsigned int*)(g), \
    (__attribute__((address_space(3))) unsigned int*)(l), 16, 0, 0)

// ---------- K1: per-class sums/counts + fused fp8 cast of Q ----------
// grid (64 kc x 4 dc), 256 thr = 4 waves. Lane = column owner; 1 row/wave
// serial; ds_add_f32 (fire-and-forget, no RMW latency chain); coalesced loads.
__global__ __launch_bounds__(256) void k_hist(
    const float* __restrict__ q, const int* __restrict__ lab,
    int* __restrict__ counts, float* __restrict__ sums, u8* __restrict__ qf8) {
  __shared__ float lsum[C_CLS * 64];    // 25.6 KB
  __shared__ int lcnt[C_CLS];
  const int kc = blockIdx.x;            // 64 chunks of 512 rows
  const int dc = blockIdx.y;            // 4 chunks of 64 cols
  const int tid = threadIdx.x, w = tid >> 6, l = tid & 63;
  for (int i = tid; i < C_CLS * 64; i += 256) lsum[i] = 0.f;
  if (dc == 0 && tid < C_CLS) lcnt[tid] = 0;
  __syncthreads();

  const int col = dc * 64 + l;
  const int k0 = kc * 512 + w * 128;
  for (int r = 0; r < 128; ++r) {
    const int k = k0 + r;
    const int c = lab[k];                               // wave-uniform
    float v = q[(size_t)k * D_DIM + col];
    atomicAdd(&lsum[c * 64 + l], v);                    // ds_add_f32, lanes->consecutive banks
    int p = __builtin_amdgcn_cvt_pk_fp8_f32(v * 16.f, v * 16.f, 0, false);
    qf8[(size_t)k * D_DIM + col] = (u8)p;               // 64B/wave coalesced
    if (dc == 0 && l == 0) atomicAdd(&lcnt[c], 1);
  }
  __syncthreads();
  for (int i = tid; i < C_CLS * 64; i += 256)
    atomicAdd(&sums[(i >> 6) * D_DIM + dc * 64 + (i & 63)], lsum[i]);
  if (dc == 0 && tid < C_CLS) atomicAdd(&counts[tid], lcnt[tid]);
}

// ---------- K2: centroid normalize ----------
__global__ void k_cnorm(const int* __restrict__ counts, const float* __restrict__ sums,
                        float* __restrict__ cnorm) {
  __shared__ float red[4];
  const int c = blockIdx.x, d = threadIdx.x;
  float cnt = (float)counts[c];
  float v = sums[c * D_DIM + d] / cnt;
  float ss = v * v;
  #pragma unroll
  for (int o = 1; o < 64; o <<= 1) ss += __shfl_xor(ss, o);
  if ((d & 63) == 0) red[d >> 6] = ss;
  __syncthreads();
  float norm = sqrtf(red[0] + red[1] + red[2] + red[3]);
  cnorm[c * D_DIM + d] = v / fmaxf(norm, 1e-12f);
}

// ---------- K3: pseudo-labels (fp32 argmax) + fused fp8 A cast ----------
__global__ void k_pseudo(const float* __restrict__ bf, const float* __restrict__ cn,
                         int* __restrict__ pseudo, u8* __restrict__ af8) {
  const int tid = threadIdx.x;
  const int rloc = tid >> 4;                    // 16 rows/block
  const int sub = tid & 15;                     // 16 lanes/row
  const int row = blockIdx.x * 16 + rloc;
  float4 a[4];
  const float4* ap = (const float4*)(bf + (size_t)row * D_DIM);
  #pragma unroll
  for (int j = 0; j < 4; ++j) a[j] = ap[sub + j * 16];
  #pragma unroll
  for (int j = 0; j < 4; ++j)
    *(unsigned int*)(af8 + (size_t)row * D_DIM + (sub + j * 16) * 4) = pk4_fp8(a[j]);
  float best = -1e30f; int bi = 0;
  for (int c = 0; c < C_CLS; ++c) {
    const float4* cp = (const float4*)(cn + c * D_DIM);
    float s = 0.f;
    #pragma unroll
    for (int j = 0; j < 4; ++j) {
      float4 b = cp[sub + j * 16];
      s += a[j].x * b.x + a[j].y * b.y + a[j].z * b.z + a[j].w * b.w;
    }
    s += __shfl_xor(s, 1); s += __shfl_xor(s, 2);
    s += __shfl_xor(s, 4); s += __shfl_xor(s, 8);
    if (s > best) { best = s; bi = c; }         // strict > = first index (jnp.argmax)
  }
  if (sub == 0) pseudo[row] = bi;
}

// ---------- K5: fused fp8 MFMA GEMM + sqrt + masked row-sums ----------
// Same structure as R9 (B via LDS broadcast, A resident, dbuf+GLDS) but fp8:
// areg 128->64 regs, total/wave ~200 < 256 -> 2 waves/SIMD (R9 was 296 -> 1,
// the 10.8% occupancy cliff). LDS tile 8KB/cb; b64 reads, swizzle (q16&3)<<5
// -> 4 lanes/8B-slot balanced = conflict-free. acc = 256*sim (inputs scaled 16x).
__global__ __launch_bounds__(256) void k_main(
    const u8* __restrict__ Af8, const u8* __restrict__ Qf8,
    const int* __restrict__ lab, const int* __restrict__ pseudo,
    float* __restrict__ S_all, float* __restrict__ S_match) {
  __shared__ u8 Bs[2][32 * 256];        // 2 x 8KB

  // XCD-bijective: 512 = 8 xcd x (4 cs x 16 rb); per-XCD: 1MB Q-slices + 1MB A in L2.
  const int bid = blockIdx.x;
  const int xcd = bid & 7, idx = bid >> 3;
  const int cs = xcd * 4 + (idx >> 4);          // 0..31 col slice (1024 cols)
  const int rb = idx & 15;                      // 0..15 row block (256 rows)

  const int tid = threadIdx.x;
  const int w = tid >> 6;                       // 4 waves, row-stacked
  const int l = tid & 63;
  const int q16 = l & 15, hi = l >> 4;
  const int rowA = rb * 256 + w * 64;
  const int colbase = cs * 1024;

  // A-fragments: 4(m) x 8(kt) x 8B = 64 regs, loaded once, resident.
  i64 areg[4][8];
  #pragma unroll
  for (int m = 0; m < 4; ++m)
    #pragma unroll
    for (int kt = 0; kt < 8; ++kt)
      areg[m][kt] = *(const i64*)(Af8 + (size_t)(rowA + m * 16 + q16) * D_DIM + kt * 32 + hi * 8);

  int psepk[4];                                 // byte-packed labels (C<256)
  #pragma unroll
  for (int m = 0; m < 4; ++m) {
    const int* pp = pseudo + rowA + m * 16 + hi * 4;
    psepk[m] = pp[0] | (pp[1] << 8) | (pp[2] << 16) | (pp[3] << 24);
  }

  float pa[4][4], pm_[4][4];
  #pragma unroll
  for (int m = 0; m < 4; ++m)
    #pragma unroll
    for (int j = 0; j < 4; ++j) { pa[m][j] = 0.f; pm_[m][j] = 0.f; }

  // Staging (rule #21): linear LDS dest, inverse-swizzled global source.
  // LDS col c (256B) holds byte y = k ^ ((c&3)<<5). Thread t, instr i:
  // dest = i*4096 + t*16 -> c = i*16 + (t>>4), y = (t&15)*16 (16B chunk, xor bit5+ safe).
  const int srow = tid >> 4;
  const int sy = ((tid & 15) * 16) ^ ((srow & 3) << 5);
  const u8* sbase = Qf8 + (size_t)(colbase + srow) * D_DIM + sy;

#define STAGE(lds, cboff)                                                 \
  {                                                                       \
    _Pragma("unroll")                                                     \
    for (int i_ = 0; i_ < 2; ++i_)                                        \
      GLDS16(sbase + (size_t)(cboff) * 8192 + i_ * 4096,                  \
             (lds) + i_ * 4096 + tid * 16);                               \
  }

  const int* lptr = lab + colbase + q16;
  const int xorm = (q16 & 3) << 5;              // read-side swizzle

  STAGE(&Bs[0][0], 0);                           // prologue

  #pragma unroll 1
  for (int cb = 0; cb < 32; ++cb) {
    __syncthreads();                             // buf[cb&1] staged (drains vmcnt)
    if (cb + 1 < 32) STAGE(&Bs[(cb + 1) & 1][0], cb + 1);   // prefetch across compute
    const int lbl0 = lptr[cb * 32];
    const int lbl1 = lptr[cb * 32 + 16];

    const u8* bs = &Bs[cb & 1][0];
    f32x4 acc[4][2];
    #pragma unroll
    for (int m = 0; m < 4; ++m)
      #pragma unroll
      for (int n = 0; n < 2; ++n)
        #pragma unroll
        for (int j = 0; j < 4; ++j) acc[m][n][j] = 0.f;

    #pragma unroll
    for (int kt = 0; kt < 8; ++kt) {
      const int koff = (kt * 32 + hi * 8) ^ xorm;
      i64 b0 = *(const i64*)(bs + q16 * 256 + koff);
      i64 b1 = *(const i64*)(bs + (16 + q16) * 256 + koff);
      #pragma unroll
      for (int m = 0; m < 4; ++m)
        acc[m][0] = __builtin_amdgcn_mfma_f32_16x16x32_fp8_fp8(areg[m][kt], b0, acc[m][0], 0, 0, 0);
      #pragma unroll
      for (int m = 0; m < 4; ++m)
        acc[m][1] = __builtin_amdgcn_mfma_f32_16x16x32_fp8_fp8(areg[m][kt], b1, acc[m][1], 0, 0, 0);
    }

    // MAE epilogue: sim = acc/256 -> mae = sqrt(2 - acc/128 + 1e-6)
    #pragma unroll
    for (int m = 0; m < 4; ++m)
      #pragma unroll
      for (int j = 0; j < 4; ++j) {
        const int p = (psepk[m] >> (8 * j)) & 255;
        float mae0 = fast_sqrt(fmaxf(__builtin_fmaf(-0.0078125f, acc[m][0][j], 2.000001f), 0.0f));
        float mae1 = fast_sqrt(fmaxf(__builtin_fmaf(-0.0078125f, acc[m][1][j], 2.000001f), 0.0f));
        pa[m][j] += mae0 + mae1;
        pm_[m][j] += (lbl0 == p ? mae0 : 0.0f) + (lbl1 == p ? mae1 : 0.0f);
      }
  }

  // once per block: reduce over 16 q-lanes, then atomics
  #pragma unroll
  for (int m = 0; m < 4; ++m)
    #pragma unroll
    for (int j = 0; j < 4; ++j) {
      float va = pa[m][j], vm = pm_[m][j];
      va += __shfl_xor(va, 1); va += __shfl_xor(va, 2);
      va += __shfl_xor(va, 4); va += __shfl_xor(va, 8);
      vm += __shfl_xor(vm, 1); vm += __shfl_xor(vm, 2);
      vm += __shfl_xor(vm, 4); vm += __shfl_xor(vm, 8);
      if (q16 == 0) {
        const int gr = rowA + m * 16 + hi * 4 + j;
        atomicAdd(&S_all[gr], va);
        atomicAdd(&S_match[gr], vm);
      }
    }
#undef STAGE
}

// ---------- K6: final scalar ----------
__global__ void k_final(const float* __restrict__ S_all, const float* __restrict__ S_match,
                        const int* __restrict__ pseudo, const int* __restrict__ counts,
                        float* __restrict__ out) {
  __shared__ float r1[16], r2[16];
  const int tid = threadIdx.x;
  float s1 = 0.f, s2 = 0.f;
  for (int b = tid; b < B_ROWS; b += 1024) {
    float cnt = (float)counts[pseudo[b]];
    float sm = S_match[b], sa = S_all[b];
    s1 += sm / (cnt + 1e-6f);
    s2 += (sa - sm) / ((float)K_Q - cnt + 1e-6f);
  }
  #pragma unroll
  for (int o = 1; o < 64; o <<= 1) { s1 += __shfl_xor(s1, o); s2 += __shfl_xor(s2, o); }
  if ((tid & 63) == 0) { r1[tid >> 6] = s1; r2[tid >> 6] = s2; }
  __syncthreads();
  if (tid == 0) {
    float t1 = 0.f, t2 = 0.f;
    #pragma unroll
    for (int i = 0; i < 16; ++i) { t1 += r1[i]; t2 += r2[i]; }
    out[0] = t1 / (float)B_ROWS + 2.0f - t2 / (float)B_ROWS;
  }
}

extern "C" void kernel_launch(void* const* d_in, const int* in_sizes, int n_in,
                              void* d_out, int out_size, void* d_ws, size_t ws_size,
                              hipStream_t stream) {
  const float* batch = (const float*)d_in[0];
  const float* queue = (const float*)d_in[1];
  const int*   lab   = (const int*)d_in[2];

  char* ws = (char*)d_ws;
  int*   counts  = (int*)  (ws + 0);
  float* sums    = (float*)(ws + 512);
  float* S_all   = (float*)(ws + 102912);
  float* S_match = (float*)(ws + 119296);
  float* cnorm   = (float*)(ws + 135680);
  int*   pseudo  = (int*)  (ws + 238080);
  u8*    Af8     = (u8*)   (ws + 254464);              // 1MB
  u8*    Qf8     = (u8*)   (ws + 254464 + 2097152);    // 8MB

  (void)hipMemsetAsync(d_ws, 0, 135680, stream);  // counts+sums+S_all+S_match

  k_hist  <<<dim3(64, 4), 256, 0, stream>>>(queue, lab, counts, sums, Qf8);
  k_cnorm <<<C_CLS, 256, 0, stream>>>(counts, sums, cnorm);
  k_pseudo<<<B_ROWS / 16, 256, 0, stream>>>(batch, cnorm, pseudo, Af8);
  k_main  <<<512, 256, 0, stream>>>(Af8, Qf8, lab, pseudo, S_all, S_match);
  k_final <<<1, 1024, 0, stream>>>(S_all, S_match, pseudo, counts, (float*)d_out);
}

// Round 11
// 169.339 us; speedup vs baseline: 2.2480x; 1.0290x over previous
//
#include <hip/hip_runtime.h>

#define B_ROWS 4096
#define K_Q    32768
#define D_DIM  256
#define C_CLS  100

typedef unsigned char u8;
typedef long i64;
typedef __attribute__((ext_vector_type(2))) long i64x2;
typedef __attribute__((ext_vector_type(4))) float f32x4;

__device__ inline float fast_sqrt(float x) { return __builtin_amdgcn_sqrtf(x); }

#define GLDS16(g, l) __builtin_amdgcn_global_load_lds( \
    (const __attribute__((address_space(1))) unsigned int*)(g), \
    (__attribute__((address_space(3))) unsigned int*)(l), 16, 0, 0)

// fp8 storage is FRAG-MAJOR within each row's 256B: element k (k=kt*32+hi*8+b,
// kt<8, hi<4, b<8) lives at byte hi*64 + kt*8 + b. Then an MFMA A/B fragment
// pair (kt,kt+1) for lane-group hi is 16 contiguous bytes.

// ---------- K1: per-class partial sums + fused fp8 cast of Q (no atomics to HBM) ----------
// grid (64 kc x 4 dc) x 512 thr (8 waves). Block: 512 rows x 64 cols; wave: 64 rows.
__global__ __launch_bounds__(512) void k_hist(
    const float* __restrict__ q, const int* __restrict__ lab,
    float* __restrict__ partial, u8* __restrict__ qf8) {
  __shared__ float lsum[C_CLS * 64];    // 25.6 KB
  const int kc = blockIdx.x, dc = blockIdx.y;
  const int tid = threadIdx.x, w = tid >> 6, l = tid & 63;
  for (int i = tid; i < C_CLS * 64; i += 512) lsum[i] = 0.f;
  __syncthreads();
  const int col = dc * 64 + l;
  // frag-major byte offset of this col within a row
  const int pcol = ((l >> 3) & 3) * 64 + (dc * 2 + (l >> 5)) * 8 + (l & 7);
  const int k0 = kc * 512 + w * 64;
  #pragma unroll 4
  for (int r = 0; r < 64; ++r) {
    const int k = k0 + r;
    const int c = lab[k];                         // wave-uniform
    float v = q[(size_t)k * D_DIM + col];
    atomicAdd(&lsum[c * 64 + l], v);              // ds_add_f32, 2-way banks = free
    int p8 = __builtin_amdgcn_cvt_pk_fp8_f32(v * 16.f, v * 16.f, 0, false);
    qf8[(size_t)k * D_DIM + pcol] = (u8)p8;       // 8x8B groups per wave
  }
  __syncthreads();
  float* pb = partial + (size_t)(kc * 4 + dc) * (C_CLS * 64);
  for (int i = tid; i < C_CLS * 64; i += 512) pb[i] = lsum[i];   // plain stores
}

// ---------- K2: counts (from lab) + partial-reduce + centroid normalize ----------
__global__ __launch_bounds__(256) void k_cnorm(
    const int* __restrict__ lab, const float* __restrict__ partial,
    int* __restrict__ counts, float* __restrict__ cnorm) {
  __shared__ float red[4];
  __shared__ int credi[4];
  const int c = blockIdx.x, d = threadIdx.x;
  int cnt = 0;
  #pragma unroll 8
  for (int i = 0; i < K_Q / 256; ++i) cnt += (lab[d + i * 256] == c) ? 1 : 0;
  #pragma unroll
  for (int o = 1; o < 64; o <<= 1) cnt += __shfl_xor(cnt, o);
  if ((d & 63) == 0) credi[d >> 6] = cnt;
  float s = 0.f;
  const int dcsel = d >> 6, low = d & 63;
  for (int kc = 0; kc < 64; ++kc)
    s += partial[(size_t)(kc * 4 + dcsel) * (C_CLS * 64) + c * 64 + low];
  __syncthreads();
  const int cnt_all = credi[0] + credi[1] + credi[2] + credi[3];
  float v = s / (float)cnt_all;
  float ss = v * v;
  #pragma unroll
  for (int o = 1; o < 64; o <<= 1) ss += __shfl_xor(ss, o);
  if ((d & 63) == 0) red[d >> 6] = ss;
  __syncthreads();
  float norm = sqrtf(red[0] + red[1] + red[2] + red[3]);
  cnorm[c * D_DIM + d] = v / fmaxf(norm, 1e-12f);
  if (d == 0) counts[c] = cnt_all;
}

// ---------- K3: pseudo-labels (fp32 argmax) + fused frag-major fp8 A cast ----------
__global__ void k_pseudo(const float* __restrict__ bf, const float* __restrict__ cn,
                         int* __restrict__ pseudo, u8* __restrict__ af8) {
  const int tid = threadIdx.x;
  const int rloc = tid >> 4, sub = tid & 15;
  const int row = blockIdx.x * 16 + rloc;
  float4 a[4];
  const float4* ap = (const float4*)(bf + (size_t)row * D_DIM);
  #pragma unroll
  for (int j = 0; j < 4; ++j) a[j] = ap[sub + j * 16];
  const int hi_ = (sub >> 1) & 3, b0_ = 4 * (sub & 1), ktb = sub >> 3;
  #pragma unroll
  for (int j = 0; j < 4; ++j) {                   // cols 4*(sub+16j)..+3
    int lo = __builtin_amdgcn_cvt_pk_fp8_f32(a[j].x * 16.f, a[j].y * 16.f, 0, false);
    int pk = __builtin_amdgcn_cvt_pk_fp8_f32(a[j].z * 16.f, a[j].w * 16.f, lo, true);
    const int kt = 2 * j + ktb;
    *(unsigned int*)(af8 + (size_t)row * D_DIM + hi_ * 64 + kt * 8 + b0_) = (unsigned int)pk;
  }
  float best = -1e30f; int bi = 0;
  for (int c = 0; c < C_CLS; ++c) {
    const float4* cp = (const float4*)(cn + c * D_DIM);
    float s = 0.f;
    #pragma unroll
    for (int j = 0; j < 4; ++j) {
      float4 b = cp[sub + j * 16];
      s += a[j].x * b.x + a[j].y * b.y + a[j].z * b.z + a[j].w * b.w;
    }
    s += __shfl_xor(s, 1); s += __shfl_xor(s, 2);
    s += __shfl_xor(s, 4); s += __shfl_xor(s, 8);
    if (s > best) { best = s; bi = c; }           // strict > = first index
  }
  if (sub == 0) pseudo[row] = bi;
}

// ---------- K5: fused fp8 MFMA GEMM + sqrt + masked row-sums ----------
// 512 blocks x 256 thr (4 waves row-stacked, 64 rows each). 16 phases of 64 cols
// (2 sub-tiles of 32). b128 LDS reads, (q16&7)-XOR swizzle (8 lanes/slot balanced).
// Zero-C first MFMA kills per-tile acc init. 1 barrier per 64 cols.
__global__ __launch_bounds__(256) void k_main(
    const u8* __restrict__ Af8, const u8* __restrict__ Qf8,
    const int* __restrict__ lab, const int* __restrict__ pseudo,
    float* __restrict__ S_all, float* __restrict__ S_match) {
  __shared__ u8 Bs[2][64 * 256];        // 2 x 16KB

  const int bid = blockIdx.x;
  const int xcd = bid & 7, idx = bid >> 3;
  const int cs = xcd * 4 + (idx >> 4);            // 0..31 col slice (1024 cols)
  const int rb = idx & 15;                        // 0..15 row block (256 rows)

  const int tid = threadIdx.x;
  const int w = tid >> 6, l = tid & 63;
  const int q16 = l & 15, hi = l >> 4;
  const int rowA = rb * 256 + w * 64;
  const int colbase = cs * 1024;

  // A-fragments: [m][kt2] i64x2 (kt pair), 64 regs, contiguous 16B loads.
  i64x2 areg[4][4];
  #pragma unroll
  for (int m = 0; m < 4; ++m) {
    const u8* ap = Af8 + (size_t)(rowA + m * 16 + q16) * D_DIM + hi * 64;
    #pragma unroll
    for (int kt2 = 0; kt2 < 4; ++kt2)
      areg[m][kt2] = *(const i64x2*)(ap + kt2 * 16);
  }

  int psepk[4];                                   // byte-packed labels (C<256)
  #pragma unroll
  for (int m = 0; m < 4; ++m) {
    const int* pp = pseudo + rowA + m * 16 + hi * 4;
    psepk[m] = pp[0] | (pp[1] << 8) | (pp[2] << 16) | (pp[3] << 24);
  }

  float pa[4][4], pm_[4][4];
  #pragma unroll
  for (int m = 0; m < 4; ++m)
    #pragma unroll
    for (int j = 0; j < 4; ++j) { pa[m][j] = 0.f; pm_[m][j] = 0.f; }

  // Staging: linear LDS dest (tid*16), inverse-swizzled global source (16B granule).
  const int scol = tid >> 4;                      // + i*16 per instr
  const int sinner = ((tid & 15) * 16) ^ ((scol & 7) << 4);
  const u8* sbase = Qf8 + (size_t)(colbase + scol) * D_DIM + sinner;

#define STAGE(buf, ph)                                                    \
  { const u8* s_ = sbase + (size_t)(ph) * (64 * D_DIM);                   \
    _Pragma("unroll")                                                     \
    for (int i_ = 0; i_ < 4; ++i_)                                        \
      GLDS16(s_ + (size_t)i_ * (16 * D_DIM), (buf) + i_ * 4096 + tid * 16); }

  const int* lptr = lab + colbase + q16;
  const int xorm = (q16 & 7) << 4;
  const f32x4 fzero = {0.f, 0.f, 0.f, 0.f};

  STAGE(&Bs[0][0], 0);                            // prologue

  #pragma unroll 1
  for (int ph = 0; ph < 16; ++ph) {
    __syncthreads();                              // buf[ph&1] staged
    if (ph + 1 < 16) STAGE(&Bs[(ph + 1) & 1][0], ph + 1);
    const u8* bs = &Bs[ph & 1][0];
    #pragma unroll
    for (int s = 0; s < 2; ++s) {
      const int lbl0 = lptr[ph * 64 + s * 32];
      const int lbl1 = lptr[ph * 64 + s * 32 + 16];
      const int cb0 = (s * 32 + q16) * 256;
      const int cb1 = (s * 32 + 16 + q16) * 256;
      f32x4 acc[4][2];
      #pragma unroll
      for (int kt2 = 0; kt2 < 4; ++kt2) {
        const int koff = (hi * 64 + kt2 * 16) ^ xorm;
        i64x2 b0 = *(const i64x2*)(bs + cb0 + koff);
        i64x2 b1 = *(const i64x2*)(bs + cb1 + koff);
        #pragma unroll
        for (int m = 0; m < 4; ++m) {
          acc[m][0] = __builtin_amdgcn_mfma_f32_16x16x32_fp8_fp8(
              areg[m][kt2].x, b0.x, kt2 == 0 ? fzero : acc[m][0], 0, 0, 0);
          acc[m][0] = __builtin_amdgcn_mfma_f32_16x16x32_fp8_fp8(
              areg[m][kt2].y, b0.y, acc[m][0], 0, 0, 0);
          acc[m][1] = __builtin_amdgcn_mfma_f32_16x16x32_fp8_fp8(
              areg[m][kt2].x, b1.x, kt2 == 0 ? fzero : acc[m][1], 0, 0, 0);
          acc[m][1] = __builtin_amdgcn_mfma_f32_16x16x32_fp8_fp8(
              areg[m][kt2].y, b1.y, acc[m][1], 0, 0, 0);
        }
      }
      // MAE epilogue: sim = acc/256 -> mae = sqrt(2 - acc/128 + 1e-6)
      #pragma unroll
      for (int m = 0; m < 4; ++m)
        #pragma unroll
        for (int j = 0; j < 4; ++j) {
          const int p = (psepk[m] >> (8 * j)) & 255;
          float mae0 = fast_sqrt(fmaxf(__builtin_fmaf(-0.0078125f, acc[m][0][j], 2.000001f), 0.0f));
          float mae1 = fast_sqrt(fmaxf(__builtin_fmaf(-0.0078125f, acc[m][1][j], 2.000001f), 0.0f));
          pa[m][j] += mae0 + mae1;
          pm_[m][j] += (lbl0 == p ? mae0 : 0.0f) + (lbl1 == p ? mae1 : 0.0f);
        }
    }
  }

  // once per block: reduce over 16 q-lanes, then atomics
  #pragma unroll
  for (int m = 0; m < 4; ++m)
    #pragma unroll
    for (int j = 0; j < 4; ++j) {
      float va = pa[m][j], vm = pm_[m][j];
      va += __shfl_xor(va, 1); va += __shfl_xor(va, 2);
      va += __shfl_xor(va, 4); va += __shfl_xor(va, 8);
      vm += __shfl_xor(vm, 1); vm += __shfl_xor(vm, 2);
      vm += __shfl_xor(vm, 4); vm += __shfl_xor(vm, 8);
      if (q16 == 0) {
        const int gr = rowA + m * 16 + hi * 4 + j;
        atomicAdd(&S_all[gr], va);
        atomicAdd(&S_match[gr], vm);
      }
    }
#undef STAGE
}

// ---------- K6: final scalar ----------
__global__ void k_final(const float* __restrict__ S_all, const float* __restrict__ S_match,
                        const int* __restrict__ pseudo, const int* __restrict__ counts,
                        float* __restrict__ out) {
  __shared__ float r1[16], r2[16];
  const int tid = threadIdx.x;
  float s1 = 0.f, s2 = 0.f;
  for (int b = tid; b < B_ROWS; b += 1024) {
    float cnt = (float)counts[pseudo[b]];
    float sm = S_match[b], sa = S_all[b];
    s1 += sm / (cnt + 1e-6f);
    s2 += (sa - sm) / ((float)K_Q - cnt + 1e-6f);
  }
  #pragma unroll
  for (int o = 1; o < 64; o <<= 1) { s1 += __shfl_xor(s1, o); s2 += __shfl_xor(s2, o); }
  if ((tid & 63) == 0) { r1[tid >> 6] = s1; r2[tid >> 6] = s2; }
  __syncthreads();
  if (tid == 0) {
    float t1 = 0.f, t2 = 0.f;
    #pragma unroll
    for (int i = 0; i < 16; ++i) { t1 += r1[i]; t2 += r2[i]; }
    out[0] = t1 / (float)B_ROWS + 2.0f - t2 / (float)B_ROWS;
  }
}

extern "C" void kernel_launch(void* const* d_in, const int* in_sizes, int n_in,
                              void* d_out, int out_size, void* d_ws, size_t ws_size,
                              hipStream_t stream) {
  const float* batch = (const float*)d_in[0];
  const float* queue = (const float*)d_in[1];
  const int*   lab   = (const int*)d_in[2];

  char* ws = (char*)d_ws;
  float* S_all   = (float*)(ws + 0);             // 16KB
  float* S_match = (float*)(ws + 16384);         // 16KB
  int*   counts  = (int*)  (ws + 32768);         // 512B
  float* cnorm   = (float*)(ws + 33280);         // 100KB
  int*   pseudo  = (int*)  (ws + 135680);        // 16KB
  u8*    Af8     = (u8*)   (ws + 152064);        // 1MB
  u8*    Qf8     = (u8*)   (ws + 1200640);       // 8MB
  float* partial = (float*)(ws + 9589248);       // 6.5MB (256 x 100 x 64 f32)

  (void)hipMemsetAsync(d_ws, 0, 32768, stream);  // S_all + S_match only

  k_hist  <<<dim3(64, 4), 512, 0, stream>>>(queue, lab, partial, Qf8);
  k_cnorm <<<C_CLS, 256, 0, stream>>>(lab, partial, counts, cnorm);
  k_pseudo<<<B_ROWS / 16, 256, 0, stream>>>(batch, cnorm, pseudo, Af8);
  k_main  <<<512, 256, 0, stream>>>(Af8, Qf8, lab, pseudo, S_all, S_match);
  k_final <<<1, 1024, 0, stream>>>(S_all, S_match, pseudo, counts, (float*)d_out);
}

// Round 12
// 155.876 us; speedup vs baseline: 2.4421x; 1.0864x over previous
//
#include <hip/hip_runtime.h>

#define B_ROWS 4096
#define K_Q    32768
#define D_DIM  256
#define C_CLS  100

typedef unsigned char u8;
typedef long i64;
typedef __attribute__((ext_vector_type(2))) long i64x2;
typedef __attribute__((ext_vector_type(4))) float f32x4;

__device__ inline float fast_sqrt(float x) { return __builtin_amdgcn_sqrtf(x); }

#define GLDS16(g, l) __builtin_amdgcn_global_load_lds( \
    (const __attribute__((address_space(1))) unsigned int*)(g), \
    (__attribute__((address_space(3))) unsigned int*)(l), 16, 0, 0)

// fp8 storage is FRAG-MAJOR within each row's 256B: element k (k=kt*32+hi*8+b,
// kt<8, hi<4, b<8) lives at byte hi*64 + kt*8 + b. An MFMA fragment kt-pair
// for lane-group hi is 16 contiguous bytes.

// ---------- K1: per-class partial sums + fused fp8 cast of Q + zero S ----------
__global__ __launch_bounds__(512) void k_hist(
    const float* __restrict__ q, const int* __restrict__ lab,
    float* __restrict__ partial, u8* __restrict__ qf8,
    float* __restrict__ S_all, float* __restrict__ S_match) {
  __shared__ float lsum[C_CLS * 64];    // 25.6 KB
  const int kc = blockIdx.x, dc = blockIdx.y;
  const int tid = threadIdx.x, w = tid >> 6, l = tid & 63;
  if (dc == 0 && tid < 64) {            // replaces the memset node (runs before k_main)
    S_all[kc * 64 + tid] = 0.f;
    S_match[kc * 64 + tid] = 0.f;
  }
  for (int i = tid; i < C_CLS * 64; i += 512) lsum[i] = 0.f;
  __syncthreads();
  const int col = dc * 64 + l;
  const int pcol = ((l >> 3) & 3) * 64 + (dc * 2 + (l >> 5)) * 8 + (l & 7);
  const int k0 = kc * 512 + w * 64;
  #pragma unroll 4
  for (int r = 0; r < 64; ++r) {
    const int k = k0 + r;
    const int c = lab[k];                         // wave-uniform
    float v = q[(size_t)k * D_DIM + col];
    atomicAdd(&lsum[c * 64 + l], v);              // ds_add_f32
    int p8 = __builtin_amdgcn_cvt_pk_fp8_f32(v * 16.f, v * 16.f, 0, false);
    qf8[(size_t)k * D_DIM + pcol] = (u8)p8;
  }
  __syncthreads();
  float* pb = partial + (size_t)(kc * 4 + dc) * (C_CLS * 64);
  for (int i = tid; i < C_CLS * 64; i += 512) pb[i] = lsum[i];
}

// ---------- K2: counts (from lab) + partial-reduce + centroid normalize ----------
__global__ __launch_bounds__(256) void k_cnorm(
    const int* __restrict__ lab, const float* __restrict__ partial,
    int* __restrict__ counts, float* __restrict__ cnorm) {
  __shared__ float red[4];
  __shared__ int credi[4];
  const int c = blockIdx.x, d = threadIdx.x;
  int cnt = 0;
  #pragma unroll 8
  for (int i = 0; i < K_Q / 256; ++i) cnt += (lab[d + i * 256] == c) ? 1 : 0;
  #pragma unroll
  for (int o = 1; o < 64; o <<= 1) cnt += __shfl_xor(cnt, o);
  if ((d & 63) == 0) credi[d >> 6] = cnt;
  float s = 0.f;
  const int dcsel = d >> 6, low = d & 63;
  for (int kc = 0; kc < 64; ++kc)
    s += partial[(size_t)(kc * 4 + dcsel) * (C_CLS * 64) + c * 64 + low];
  __syncthreads();
  const int cnt_all = credi[0] + credi[1] + credi[2] + credi[3];
  float v = s / (float)cnt_all;
  float ss = v * v;
  #pragma unroll
  for (int o = 1; o < 64; o <<= 1) ss += __shfl_xor(ss, o);
  if ((d & 63) == 0) red[d >> 6] = ss;
  __syncthreads();
  float norm = sqrtf(red[0] + red[1] + red[2] + red[3]);
  cnorm[c * D_DIM + d] = v / fmaxf(norm, 1e-12f);
  if (d == 0) counts[c] = cnt_all;
}

// ---------- K3: pseudo-labels (fp32 argmax, class-pair ILP) + frag-major fp8 A cast ----------
__global__ void k_pseudo(const float* __restrict__ bf, const float* __restrict__ cn,
                         int* __restrict__ pseudo, u8* __restrict__ af8) {
  const int tid = threadIdx.x;
  const int rloc = tid >> 4, sub = tid & 15;
  const int row = blockIdx.x * 16 + rloc;
  float4 a[4];
  const float4* ap = (const float4*)(bf + (size_t)row * D_DIM);
  #pragma unroll
  for (int j = 0; j < 4; ++j) a[j] = ap[sub + j * 16];
  const int hi_ = (sub >> 1) & 3, b0_ = 4 * (sub & 1), ktb = sub >> 3;
  #pragma unroll
  for (int j = 0; j < 4; ++j) {
    int lo = __builtin_amdgcn_cvt_pk_fp8_f32(a[j].x * 16.f, a[j].y * 16.f, 0, false);
    int pk = __builtin_amdgcn_cvt_pk_fp8_f32(a[j].z * 16.f, a[j].w * 16.f, lo, true);
    const int kt = 2 * j + ktb;
    *(unsigned int*)(af8 + (size_t)row * D_DIM + hi_ * 64 + kt * 8 + b0_) = (unsigned int)pk;
  }
  float best = -1e30f; int bi = 0;
  for (int c = 0; c < C_CLS; c += 2) {            // pair ILP: 2 independent shfl chains
    const float4* cp0 = (const float4*)(cn + c * D_DIM);
    const float4* cp1 = (const float4*)(cn + (c + 1) * D_DIM);
    float s0 = 0.f, s1 = 0.f;
    #pragma unroll
    for (int j = 0; j < 4; ++j) {
      float4 b0 = cp0[sub + j * 16];
      float4 b1 = cp1[sub + j * 16];
      s0 += a[j].x * b0.x + a[j].y * b0.y + a[j].z * b0.z + a[j].w * b0.w;
      s1 += a[j].x * b1.x + a[j].y * b1.y + a[j].z * b1.z + a[j].w * b1.w;
    }
    s0 += __shfl_xor(s0, 1); s1 += __shfl_xor(s1, 1);
    s0 += __shfl_xor(s0, 2); s1 += __shfl_xor(s1, 2);
    s0 += __shfl_xor(s0, 4); s1 += __shfl_xor(s1, 4);
    s0 += __shfl_xor(s0, 8); s1 += __shfl_xor(s1, 8);
    if (s0 > best) { best = s0; bi = c; }         // order preserves first-index semantics
    if (s1 > best) { best = s1; bi = c + 1; }
  }
  if (sub == 0) pseudo[row] = bi;
}

// ---------- K5: fused fp8 MFMA GEMM + sqrt + masked row-sums ----------
// 512 blocks x 512 thr (8 waves row-stacked, 32 rows each = 256 rows/block),
// 16 phases of 64 cols. Wave tile m2 x n4: areg 32 regs, acc 32, pa/pm 16
// -> ~120 regs/wave, __launch_bounds__(512,4) => 4 waves/SIMD, 2 blocks/CU
// (R11 was ~190 regs -> 2 waves/SIMD, 18% occupancy: VALU epilogue exposed).
__global__ __launch_bounds__(512, 4) void k_main(
    const u8* __restrict__ Af8, const u8* __restrict__ Qf8,
    const int* __restrict__ lab, const int* __restrict__ pseudo,
    float* __restrict__ S_all, float* __restrict__ S_match) {
  __shared__ u8 Bs[2][64 * 256];        // 2 x 16KB

  const int bid = blockIdx.x;
  const int xcd = bid & 7, idx = bid >> 3;
  const int cs = xcd * 4 + (idx >> 4);            // 0..31 col slice (1024 cols)
  const int rb = idx & 15;                        // 0..15 row block (256 rows)

  const int tid = threadIdx.x;
  const int w = tid >> 6, l = tid & 63;
  const int q16 = l & 15, hi = l >> 4;
  const int rowA = rb * 256 + w * 32;             // wave's 32 rows
  const int colbase = cs * 1024;

  // A-fragments: [m][kt2] i64x2, 32 regs, contiguous 16B loads.
  i64x2 areg[2][4];
  #pragma unroll
  for (int m = 0; m < 2; ++m) {
    const u8* ap = Af8 + (size_t)(rowA + m * 16 + q16) * D_DIM + hi * 64;
    #pragma unroll
    for (int kt2 = 0; kt2 < 4; ++kt2)
      areg[m][kt2] = *(const i64x2*)(ap + kt2 * 16);
  }

  int psepk[2];                                   // byte-packed labels (C<256)
  #pragma unroll
  for (int m = 0; m < 2; ++m) {
    const int* pp = pseudo + rowA + m * 16 + hi * 4;
    psepk[m] = pp[0] | (pp[1] << 8) | (pp[2] << 16) | (pp[3] << 24);
  }

  float pa[2][4], pm_[2][4];
  #pragma unroll
  for (int m = 0; m < 2; ++m)
    #pragma unroll
    for (int j = 0; j < 4; ++j) { pa[m][j] = 0.f; pm_[m][j] = 0.f; }

  // Staging: linear LDS dest (chunk j = i*512+tid -> byte j*16), inverse-swizzled
  // global source; source and dest both advance by 8192 per instr.
  const int scol = tid >> 4;                      // 0..31
  const int sinner = ((tid & 15) * 16) ^ ((scol & 7) << 4);
  const u8* sbase = Qf8 + (size_t)(colbase + scol) * D_DIM + sinner;

#define STAGE(buf, ph)                                                    \
  { const u8* s_ = sbase + (size_t)(ph) * (64 * D_DIM);                   \
    GLDS16(s_,                 (buf) + tid * 16);                         \
    GLDS16(s_ + 32 * D_DIM,    (buf) + 8192 + tid * 16); }

  const int* lptr = lab + colbase + q16;
  const int xorm = (q16 & 7) << 4;
  const f32x4 fzero = {0.f, 0.f, 0.f, 0.f};

  STAGE(&Bs[0][0], 0);                            // prologue

  #pragma unroll 1
  for (int ph = 0; ph < 16; ++ph) {
    __syncthreads();                              // buf[ph&1] staged
    if (ph + 1 < 16) STAGE(&Bs[(ph + 1) & 1][0], ph + 1);
    const u8* bs = &Bs[ph & 1][0];
    int lbl[4];
    #pragma unroll
    for (int n = 0; n < 4; ++n) lbl[n] = lptr[ph * 64 + n * 16];

    f32x4 acc[2][4];
    #pragma unroll
    for (int kt2 = 0; kt2 < 4; ++kt2) {
      const int koff = (hi * 64 + kt2 * 16) ^ xorm;
      i64x2 b[4];
      #pragma unroll
      for (int n = 0; n < 4; ++n)
        b[n] = *(const i64x2*)(bs + (n * 16 + q16) * 256 + koff);
      #pragma unroll
      for (int m = 0; m < 2; ++m)
        #pragma unroll
        for (int n = 0; n < 4; ++n) {
          acc[m][n] = __builtin_amdgcn_mfma_f32_16x16x32_fp8_fp8(
              areg[m][kt2].x, b[n].x, kt2 == 0 ? fzero : acc[m][n], 0, 0, 0);
          acc[m][n] = __builtin_amdgcn_mfma_f32_16x16x32_fp8_fp8(
              areg[m][kt2].y, b[n].y, acc[m][n], 0, 0, 0);
        }
    }

    // MAE epilogue: sim = acc/256 -> mae = sqrt(2 - acc/128 + 1e-6)
    #pragma unroll
    for (int m = 0; m < 2; ++m)
      #pragma unroll
      for (int j = 0; j < 4; ++j) {
        const int p = (psepk[m] >> (8 * j)) & 255;
        #pragma unroll
        for (int n = 0; n < 4; ++n) {
          float mae = fast_sqrt(fmaxf(__builtin_fmaf(-0.0078125f, acc[m][n][j], 2.000001f), 0.0f));
          pa[m][j] += mae;
          pm_[m][j] += (lbl[n] == p ? mae : 0.0f);
        }
      }
  }

  // once per block: reduce over 16 q-lanes, then atomics
  #pragma unroll
  for (int m = 0; m < 2; ++m)
    #pragma unroll
    for (int j = 0; j < 4; ++j) {
      float va = pa[m][j], vm = pm_[m][j];
      va += __shfl_xor(va, 1); va += __shfl_xor(va, 2);
      va += __shfl_xor(va, 4); va += __shfl_xor(va, 8);
      vm += __shfl_xor(vm, 1); vm += __shfl_xor(vm, 2);
      vm += __shfl_xor(vm, 4); vm += __shfl_xor(vm, 8);
      if (q16 == 0) {
        const int gr = rowA + m * 16 + hi * 4 + j;
        atomicAdd(&S_all[gr], va);
        atomicAdd(&S_match[gr], vm);
      }
    }
#undef STAGE
}

// ---------- K6: final scalar ----------
__global__ void k_final(const float* __restrict__ S_all, const float* __restrict__ S_match,
                        const int* __restrict__ pseudo, const int* __restrict__ counts,
                        float* __restrict__ out) {
  __shared__ float r1[16], r2[16];
  const int tid = threadIdx.x;
  float s1 = 0.f, s2 = 0.f;
  for (int b = tid; b < B_ROWS; b += 1024) {
    float cnt = (float)counts[pseudo[b]];
    float sm = S_match[b], sa = S_all[b];
    s1 += sm / (cnt + 1e-6f);
    s2 += (sa - sm) / ((float)K_Q - cnt + 1e-6f);
  }
  #pragma unroll
  for (int o = 1; o < 64; o <<= 1) { s1 += __shfl_xor(s1, o); s2 += __shfl_xor(s2, o); }
  if ((tid & 63) == 0) { r1[tid >> 6] = s1; r2[tid >> 6] = s2; }
  __syncthreads();
  if (tid == 0) {
    float t1 = 0.f, t2 = 0.f;
    #pragma unroll
    for (int i = 0; i < 16; ++i) { t1 += r1[i]; t2 += r2[i]; }
    out[0] = t1 / (float)B_ROWS + 2.0f - t2 / (float)B_ROWS;
  }
}

extern "C" void kernel_launch(void* const* d_in, const int* in_sizes, int n_in,
                              void* d_out, int out_size, void* d_ws, size_t ws_size,
                              hipStream_t stream) {
  const float* batch = (const float*)d_in[0];
  const float* queue = (const float*)d_in[1];
  const int*   lab   = (const int*)d_in[2];

  char* ws = (char*)d_ws;
  float* S_all   = (float*)(ws + 0);             // 16KB (zeroed by k_hist)
  float* S_match = (float*)(ws + 16384);         // 16KB (zeroed by k_hist)
  int*   counts  = (int*)  (ws + 32768);         // 512B (written by k_cnorm)
  float* cnorm   = (float*)(ws + 33280);         // 100KB
  int*   pseudo  = (int*)  (ws + 135680);        // 16KB
  u8*    Af8     = (u8*)   (ws + 152064);        // 1MB
  u8*    Qf8     = (u8*)   (ws + 1200640);       // 8MB
  float* partial = (float*)(ws + 9589248);       // 6.5MB

  k_hist  <<<dim3(64, 4), 512, 0, stream>>>(queue, lab, partial, Qf8, S_all, S_match);
  k_cnorm <<<C_CLS, 256, 0, stream>>>(lab, partial, counts, cnorm);
  k_pseudo<<<B_ROWS / 16, 256, 0, stream>>>(batch, cnorm, pseudo, Af8);
  k_main  <<<512, 512, 0, stream>>>(Af8, Qf8, lab, pseudo, S_all, S_match);
  k_final <<<1, 1024, 0, stream>>>(S_all, S_match, pseudo, counts, (float*)d_out);
}